// Round 5
// baseline (1402.704 us; speedup 1.0000x reference)
//
#include <hip/hip_runtime.h>
#include <math.h>

#define BS   8
#define TT   1024
#define DD   512
#define HH   8
#define LL   4
#define FFD  2048
#define NCC  10
#define MM   (BS*TT)
#define MDl  ((long)MM*DD)

typedef unsigned short u16;
typedef short  short8 __attribute__((ext_vector_type(8)));
typedef float  f32x4  __attribute__((ext_vector_type(4)));
typedef u16    u16x8  __attribute__((ext_vector_type(8)));
typedef u16    u16x4  __attribute__((ext_vector_type(4)));

static __device__ __forceinline__ u16 f2b(float f) {
    union { float f; unsigned u; } x; x.f = f;
    unsigned r = x.u + 0x7FFFu + ((x.u >> 16) & 1u);   // RNE
    return (u16)(r >> 16);
}
// round-half-up: 2 insts, differs from RNE only on exact ties (negligible)
static __device__ __forceinline__ u16 f2b_fast(float f) {
    union { float f; unsigned u; } x; x.f = f;
    return (u16)((x.u + 0x8000u) >> 16);
}
static __device__ __forceinline__ float b2f(u16 u) {
    union { unsigned u; float f; } x; x.u = ((unsigned)u) << 16;
    return x.f;
}

// ---------------------------------------------------------------------------
// Embedding + sinusoidal positional encoding  (X fp32)
// ---------------------------------------------------------------------------
__global__ __launch_bounds__(256)
void embed_kernel(const int* __restrict__ tok, const float* __restrict__ emb,
                  float* __restrict__ X) {
    int i = blockIdx.x * 256 + threadIdx.x;
    int d = i & (DD - 1);
    int row = i >> 9;
    int t = row & (TT - 1);
    int j = d >> 1;
    float freq = __expf((float)(2 * j) * (-9.210340371976184f / 512.0f));
    float ang = (float)t * freq;
    float pe = (d & 1) ? cosf(ang) : sinf(ang);
    X[i] = emb[(long)tok[row] * DD + d] + pe;
}

// ---------------------------------------------------------------------------
// LayerNorm over D=512; OUTBF: 1 -> bf16 out, 0 -> fp32 out
// ---------------------------------------------------------------------------
template<int OUTBF>
__global__ __launch_bounds__(256)
void ln_kernel(const float* __restrict__ in, void* __restrict__ outp,
               const float* __restrict__ g, const float* __restrict__ b) {
    int row = blockIdx.x;
    int tid = threadIdx.x;
    const float* x = in + (long)row * DD;
    float x1 = x[tid], x2 = x[tid + 256];
    __shared__ float red[256], red2[256];
    red[tid] = x1 + x2;
    red2[tid] = x1 * x1 + x2 * x2;
    __syncthreads();
    for (int st = 128; st > 0; st >>= 1) {
        if (tid < st) { red[tid] += red[tid + st]; red2[tid] += red2[tid + st]; }
        __syncthreads();
    }
    float mean = red[0] * (1.0f / DD);
    float var = red2[0] * (1.0f / DD) - mean * mean;
    float rstd = rsqrtf(var + 1e-5f);
    float y1 = (x1 - mean) * rstd * g[tid] + b[tid];
    float y2 = (x2 - mean) * rstd * g[tid + 256] + b[tid + 256];
    if (OUTBF) {
        u16* o = (u16*)outp + (long)row * DD;
        o[tid] = f2b(y1); o[tid + 256] = f2b(y2);
    } else {
        float* o = (float*)outp + (long)row * DD;
        o[tid] = y1; o[tid + 256] = y2;
    }
}

// ---------------------------------------------------------------------------
// bf16 MFMA GEMM: C[M=8192, N] = epi(A[M,K] @ W), W given as WT[N][K] bf16.
// 128x128 tile, BK=64, 256 thr. Register-prefetch pipeline: tile k+1 is
// loaded into VGPRs while tile k computes (plain loads are NOT drained by
// s_barrier, unlike global_load_lds). LDS chunk c of row r at slot c^(r&7)
// -> conflict-free ds_read_b128 frags and 2-way (free) staging writes.
// ---------------------------------------------------------------------------
template<int OUTBF, int HAS_BIAS, int ACT, int HAS_RES>
__global__ __launch_bounds__(256, 2)
void mfma_gemm(const u16* __restrict__ A, const u16* __restrict__ BT,
               const float* __restrict__ bias, const float* __restrict__ R,
               void* __restrict__ Cout, int N, int K) {
    __shared__ __align__(16) u16 lds[17408];   // As(8192)+Bs(8192) | Cs(128x136)
    u16* As = lds;
    u16* Bs = lds + 8192;
    const int tid = threadIdx.x;
    const int lane = tid & 63;
    const int w = tid >> 6;
    const long bm = (long)blockIdx.y * 128;
    const long bn = (long)blockIdx.x * 128;

    f32x4 acc[4][4];
#pragma unroll
    for (int i = 0; i < 4; ++i)
#pragma unroll
        for (int j = 0; j < 4; ++j) acc[i][j] = {0.f, 0.f, 0.f, 0.f};

    // staging: thread -> row tid>>1, 4 chunks (tid&1)*4 + j (64B contiguous)
    const int srow = tid >> 1;
    const int sc0 = (tid & 1) * 4;
    const u16* Ag = A + (bm + srow) * K + sc0 * 8;
    const u16* Bg = BT + (bn + srow) * K + sc0 * 8;
    int soff[4];
#pragma unroll
    for (int j = 0; j < 4; ++j)
        soff[j] = srow * 64 + ((sc0 + j) ^ (srow & 7)) * 8;

    const int fr = lane & 15;
    const int g = lane >> 4;
    const int am0 = (w >> 1) * 64 + fr;
    const int bn0 = (w & 1) * 64 + fr;
    const int sw = fr & 7;

    u16x8 sa[2][4], sb[2][4];
#pragma unroll
    for (int j = 0; j < 4; ++j) {          // prologue: tile k0=0 -> regs
        sa[0][j] = *(const u16x8*)(Ag + j * 8);
        sb[0][j] = *(const u16x8*)(Bg + j * 8);
    }

    for (int k0 = 0; k0 < K; k0 += 128) {
#pragma unroll
        for (int half = 0; half < 2; ++half) {
            const int cb = half, nb = half ^ 1;
            __syncthreads();               // prior frag reads done
#pragma unroll
            for (int j = 0; j < 4; ++j) {
                *(u16x8*)&As[soff[j]] = sa[cb][j];
                *(u16x8*)&Bs[soff[j]] = sb[cb][j];
            }
            const int knext = k0 + (half + 1) * 64;
            if (knext < K) {               // prefetch next tile -> regs
#pragma unroll
                for (int j = 0; j < 4; ++j) {
                    sa[nb][j] = *(const u16x8*)(Ag + knext + j * 8);
                    sb[nb][j] = *(const u16x8*)(Bg + knext + j * 8);
                }
            }
            __syncthreads();               // staged tile visible
#pragma unroll
            for (int kk = 0; kk < 2; ++kk) {
                const int pos = ((kk << 2) + g) ^ sw;
                short8 af[4], bfv[4];
#pragma unroll
                for (int mi = 0; mi < 4; ++mi)
                    af[mi] = *(const short8*)&As[(am0 + mi * 16) * 64 + pos * 8];
#pragma unroll
                for (int ni = 0; ni < 4; ++ni)
                    bfv[ni] = *(const short8*)&Bs[(bn0 + ni * 16) * 64 + pos * 8];
#pragma unroll
                for (int mi = 0; mi < 4; ++mi)
#pragma unroll
                    for (int ni = 0; ni < 4; ++ni)
                        acc[mi][ni] = __builtin_amdgcn_mfma_f32_16x16x32_bf16(
                            af[mi], bfv[ni], acc[mi][ni], 0, 0, 0);
            }
        }
    }

    // C/D layout: col = lane&15, row = (lane>>4)*4 + reg
    const int erow0 = (w >> 1) * 64 + g * 4;
    const int ecol0 = (w & 1) * 64 + fr;

    if (OUTBF) {
        __syncthreads();
#pragma unroll
        for (int ni = 0; ni < 4; ++ni) {
            const long col = bn + ecol0 + ni * 16;
            float bv = 0.f;
            if (HAS_BIAS) bv = bias[col];
#pragma unroll
            for (int mi = 0; mi < 4; ++mi)
#pragma unroll
                for (int r = 0; r < 4; ++r) {
                    const int row = erow0 + mi * 16 + r;
                    float v = acc[mi][ni][r];
                    if (HAS_BIAS) v += bv;
                    if (ACT == 1) v = 0.5f * v * (1.0f + erff(v * 0.70710678118654752f));
                    if (ACT == 2) v = tanhf(v);
                    if (HAS_RES) v += R[(bm + row) * N + col];
                    lds[row * 136 + ecol0 + ni * 16] = f2b(v);
                }
        }
        __syncthreads();
        const int srow2 = tid >> 4;
        const int sch2 = tid & 15;
        u16* Cp = (u16*)Cout;
#pragma unroll
        for (int rr = 0; rr < 8; ++rr) {
            const int row = srow2 + rr * 16;
            u16x8 vv = *(const u16x8*)&lds[row * 136 + sch2 * 8];
            *(u16x8*)(Cp + (bm + row) * N + bn + sch2 * 8) = vv;
        }
    } else {
#pragma unroll
        for (int ni = 0; ni < 4; ++ni) {
            const long col = bn + ecol0 + ni * 16;
            float bv = 0.f;
            if (HAS_BIAS) bv = bias[col];
#pragma unroll
            for (int mi = 0; mi < 4; ++mi)
#pragma unroll
                for (int r = 0; r < 4; ++r) {
                    const long row = bm + erow0 + mi * 16 + r;
                    float v = acc[mi][ni][r];
                    if (HAS_BIAS) v += bv;
                    if (ACT == 1) v = 0.5f * v * (1.0f + erff(v * 0.70710678118654752f));
                    if (ACT == 2) v = tanhf(v);
                    if (HAS_RES) v += R[row * N + col];
                    ((float*)Cout)[row * N + col] = v;
                }
        }
    }
}

// ---------------------------------------------------------------------------
// MFMA flash attention with register-prefetch pipeline.
// QKV packed [M][1536] bf16 (q|k|v), O [M][512] bf16.
// Block = (128 q, h, b); K/V tile kt+1 loaded into VGPRs during compute of kt.
// Ks[key][64] XOR-swizzled (chunk c at slot c^(key&7)): conflict-free frags.
// Vt staged via key-pair packing (8 ds_write_b32/thread).
// No-max softmax (scores bounded), lsum in fp32, P via round-half-up.
// ---------------------------------------------------------------------------
__global__ __launch_bounds__(256, 2)
void attn_kernel(const u16* __restrict__ QKV, u16* __restrict__ O) {
    const int qblk = blockIdx.x;
    const int h = blockIdx.y;
    const int b = blockIdx.z;
    const int tid = threadIdx.x;
    const int lane = tid & 63;
    const int w = tid >> 6;
    const int fr = lane & 15;
    const int g = lane >> 4;
    const int q8 = g * 8;

    __shared__ __align__(16) u16 Ks[64 * 64];     // [key][64d] swizzled
    __shared__ __align__(16) u16 Vt[64 * 72];     // [d][key] padded
    __shared__ __align__(16) u16 Pw[4][32 * 72];  // per-wave P[q][key]

    const long rowb = (long)b * TT;
    const int wq0 = qblk * 128 + w * 32;

    // Q A-frags (once)
    short8 qf[2][2];
#pragma unroll
    for (int qt = 0; qt < 2; ++qt)
#pragma unroll
        for (int hf = 0; hf < 2; ++hf)
            qf[qt][hf] = *(const short8*)(QKV + (rowb + wq0 + qt * 16 + fr) * 1536
                                          + h * 64 + hf * 32 + q8);

    f32x4 accO[2][4];
    float lsum[2][4];
#pragma unroll
    for (int qt = 0; qt < 2; ++qt) {
#pragma unroll
        for (int nt = 0; nt < 4; ++nt) accO[qt][nt] = {0.f, 0.f, 0.f, 0.f};
#pragma unroll
        for (int r = 0; r < 4; ++r) lsum[qt][r] = 0.f;
    }

    // staging assignments
    const int skey = tid >> 2;              // 0..63
    const int skc = (tid & 3) * 2;          // chunks skc, skc+1
    const int koff0 = skey * 64 + ((skc ^ (skey & 7)) * 8);
    const int koff1 = skey * 64 + (((skc + 1) ^ (skey & 7)) * 8);
    const int vkp = tid & 31;               // keys 2vkp, 2vkp+1
    const int vd0 = (tid >> 5) * 8;         // 8 d values

#define LOAD_KV(kt_, kr_, vr_) do {                                            \
        const long tb_ = (rowb + (long)(kt_) * 64) * 1536 + h * 64;            \
        const u16* kp_ = QKV + tb_ + 512 + (long)skey * 1536 + skc * 8;        \
        kr_[0] = *(const u16x8*)kp_;                                           \
        kr_[1] = *(const u16x8*)(kp_ + 8);                                     \
        const u16* vp_ = QKV + tb_ + 1024 + (long)(vkp * 2) * 1536 + vd0;      \
        vr_[0] = *(const u16x8*)vp_;                                           \
        vr_[1] = *(const u16x8*)(vp_ + 1536);                                  \
    } while (0)

    u16x8 kr[2][2], vr[2][2];
    LOAD_KV(0, kr[0], vr[0]);

#pragma unroll
    for (int kt = 0; kt < 16; ++kt) {
        const int cb = kt & 1, nb = cb ^ 1;
        __syncthreads();                    // prior tile fully consumed
        *(u16x8*)&Ks[koff0] = kr[cb][0];
        *(u16x8*)&Ks[koff1] = kr[cb][1];
        {
            unsigned* Vt32 = (unsigned*)Vt;
#pragma unroll
            for (int j = 0; j < 8; ++j)
                Vt32[(vd0 + j) * 36 + vkp] =
                    (unsigned)vr[cb][0][j] | ((unsigned)vr[cb][1][j] << 16);
        }
        if (kt < 15) LOAD_KV(kt + 1, kr[nb], vr[nb]);   // in flight thru compute
        __syncthreads();                    // staged tile visible

        // S = Q K^T
        f32x4 accS[2][4];
#pragma unroll
        for (int qt = 0; qt < 2; ++qt)
#pragma unroll
            for (int n = 0; n < 4; ++n) accS[qt][n] = {0.f, 0.f, 0.f, 0.f};
#pragma unroll
        for (int n = 0; n < 4; ++n)
#pragma unroll
            for (int hf = 0; hf < 2; ++hf) {
                short8 bk = *(const short8*)&Ks[(n * 16 + fr) * 64
                                                + ((((hf << 2) + g) ^ (fr & 7)) * 8)];
                accS[0][n] = __builtin_amdgcn_mfma_f32_16x16x32_bf16(qf[0][hf], bk, accS[0][n], 0, 0, 0);
                accS[1][n] = __builtin_amdgcn_mfma_f32_16x16x32_bf16(qf[1][hf], bk, accS[1][n], 0, 0, 0);
            }
        // p = exp(s/8); lsum in fp32; P stored bf16 (half-up round)
#pragma unroll
        for (int qt = 0; qt < 2; ++qt)
#pragma unroll
            for (int r = 0; r < 4; ++r) {
                int prow = qt * 16 + g * 4 + r;
#pragma unroll
                for (int n = 0; n < 4; ++n) {
                    float pv = exp2f(accS[qt][n][r] * 0.18033688011112042f);
                    lsum[qt][r] += pv;
                    Pw[w][prow * 72 + n * 16 + fr] = f2b_fast(pv);
                }
            }
        // O += P V
#pragma unroll
        for (int hf = 0; hf < 2; ++hf) {
            short8 pa0 = *(const short8*)&Pw[w][fr * 72 + hf * 32 + q8];
            short8 pa1 = *(const short8*)&Pw[w][(16 + fr) * 72 + hf * 32 + q8];
#pragma unroll
            for (int nt = 0; nt < 4; ++nt) {
                short8 bv = *(const short8*)&Vt[(nt * 16 + fr) * 72 + hf * 32 + q8];
                accO[0][nt] = __builtin_amdgcn_mfma_f32_16x16x32_bf16(pa0, bv, accO[0][nt], 0, 0, 0);
                accO[1][nt] = __builtin_amdgcn_mfma_f32_16x16x32_bf16(pa1, bv, accO[1][nt], 0, 0, 0);
            }
        }
    }
#undef LOAD_KV

#pragma unroll
    for (int qt = 0; qt < 2; ++qt)
#pragma unroll
        for (int r = 0; r < 4; ++r) {
            float s = lsum[qt][r];
            s += __shfl_xor(s, 1, 64);
            s += __shfl_xor(s, 2, 64);
            s += __shfl_xor(s, 4, 64);
            s += __shfl_xor(s, 8, 64);
            lsum[qt][r] = 1.0f / s;
        }
#pragma unroll
    for (int qt = 0; qt < 2; ++qt)
#pragma unroll
        for (int nt = 0; nt < 4; ++nt)
#pragma unroll
            for (int r = 0; r < 4; ++r) {
                long row = rowb + wq0 + qt * 16 + g * 4 + r;
                O[row * DD + h * 64 + nt * 16 + fr] = f2b(accO[qt][nt][r] * lsum[qt][r]);
            }
}

// ---------------------------------------------------------------------------
// Weight prep. wprep512_kernel: nineteen 512x512 transposes via pointer table.
// ---------------------------------------------------------------------------
struct WP   { const float* s; u16* d; };
struct WTbl { WP e[19]; };

__global__ __launch_bounds__(256)
void wprep512_kernel(WTbl tbl) {
    const float* src = tbl.e[blockIdx.z].s;
    u16* dst = tbl.e[blockIdx.z].d;
    int k0 = blockIdx.y * 32, n0 = blockIdx.x * 32;
    __shared__ float tile[32][33];
    int tx = threadIdx.x & 31, ty = threadIdx.x >> 5;
#pragma unroll
    for (int i = 0; i < 4; ++i)
        tile[ty + 8 * i][tx] = src[(long)(k0 + ty + 8 * i) * 512 + n0 + tx];
    __syncthreads();
#pragma unroll
    for (int i = 0; i < 4; ++i) {
        int r = ty + 8 * i;
        dst[(long)(n0 + r) * 512 + k0 + tx] = f2b(tile[tx][r]);
    }
}

__global__ __launch_bounds__(256)
void wprep_kernel(const float* __restrict__ src, u16* __restrict__ dst,
                  int K, int N, long srcLS, long dstLS) {
    int l = blockIdx.z;
    src += (long)l * srcLS;
    dst += (long)l * dstLS;
    int k0 = blockIdx.y * 32, n0 = blockIdx.x * 32;
    __shared__ float tile[32][33];
    int tx = threadIdx.x & 31, ty = threadIdx.x >> 5;
#pragma unroll
    for (int i = 0; i < 4; ++i)
        tile[ty + 8 * i][tx] = src[(long)(k0 + ty + 8 * i) * N + n0 + tx];
    __syncthreads();
#pragma unroll
    for (int i = 0; i < 4; ++i) {
        int r = ty + 8 * i;
        dst[(long)(n0 + r) * K + k0 + tx] = f2b(tile[tx][r]);
    }
}

__global__ __launch_bounds__(256)
void bprep_kernel(const float* __restrict__ bq, const float* __restrict__ bk,
                  const float* __restrict__ bv, float* __restrict__ dst) {
    int i = blockIdx.x * 256 + threadIdx.x;
    int l = i / 1536, j = i - l * 1536;
    float v = (j < 512) ? bq[l * 512 + j]
            : (j < 1024) ? bk[l * 512 + j - 512]
                         : bv[l * 512 + j - 1024];
    dst[i] = v;
}

__global__ __launch_bounds__(256)
void f2b_kernel(const float* __restrict__ in, u16* __restrict__ out, int n) {
    int i = blockIdx.x * 256 + threadIdx.x;
    if (i < n) out[i] = f2b(in[i]);
}

__global__ __launch_bounds__(256)
void zero_kernel(float* __restrict__ p, int n) {
    int i = blockIdx.x * 256 + threadIdx.x;
    if (i < n) p[i] = 0.0f;
}

__global__ __launch_bounds__(256)
void colmean_kernel(const float* __restrict__ Hn, float* __restrict__ XM) {
    int blk = blockIdx.x;
    int b = blk >> 5;
    int r0 = (blk & 31) * 32;
    int tid = threadIdx.x;
    float acc0 = 0.0f, acc1 = 0.0f;
    for (int r = 0; r < 32; ++r) {
        long off = ((long)b * TT + r0 + r) * DD + tid;
        acc0 += Hn[off];
        acc1 += Hn[off + 256];
    }
    atomicAdd(&XM[b * DD + tid], acc0);
    atomicAdd(&XM[b * DD + tid + 256], acc1);
}

__global__ __launch_bounds__(256)
void cls_kernel(const float* __restrict__ XM, const float* __restrict__ W,
                const float* __restrict__ bias, float* __restrict__ out) {
    int b = blockIdx.x;
    int tid = threadIdx.x;
    __shared__ float xm[DD];
    xm[tid] = XM[b * DD + tid] * (1.0f / TT);
    xm[tid + 256] = XM[b * DD + tid + 256] * (1.0f / TT);
    __syncthreads();
    if (tid < NCC) {
        float s = bias[tid];
        for (int d = 0; d < DD; ++d) s += xm[d] * W[d * NCC + tid];
        out[b * NCC + tid] = s;
    }
}

// ---------------------------------------------------------------------------
extern "C" void kernel_launch(void* const* d_in, const int* in_sizes, int n_in,
                              void* d_out, int out_size, void* d_ws, size_t ws_size,
                              hipStream_t stream) {
    const int*   tokens  = (const int*)d_in[0];
    const float* emb     = (const float*)d_in[1];
    const float* Wq      = (const float*)d_in[2];
    const float* bq      = (const float*)d_in[3];
    const float* Wk      = (const float*)d_in[4];
    const float* bk      = (const float*)d_in[5];
    const float* Wv      = (const float*)d_in[6];
    const float* bv      = (const float*)d_in[7];
    const float* Wo      = (const float*)d_in[8];
    const float* bo      = (const float*)d_in[9];
    const float* ln1_g   = (const float*)d_in[10];
    const float* ln1_b   = (const float*)d_in[11];
    const float* ln2_g   = (const float*)d_in[12];
    const float* ln2_b   = (const float*)d_in[13];
    const float* W1      = (const float*)d_in[14];
    const float* b1      = (const float*)d_in[15];
    const float* W2      = (const float*)d_in[16];
    const float* b2      = (const float*)d_in[17];
    const float* heavy_w = (const float*)d_in[18];
    const float* heavy_b = (const float*)d_in[19];
    const float* heavy_a1= (const float*)d_in[20];
    const float* heavy_a2= (const float*)d_in[21];
    const float* norm_g  = (const float*)d_in[22];
    const float* norm_b  = (const float*)d_in[23];
    const float* cls_W   = (const float*)d_in[24];
    const float* cls_b   = (const float*)d_in[25];
    float* out = (float*)d_out;

    char* p = (char*)d_ws;
    float* X    = (float*)p;  p += MDl * 4;
    u16*   Hh   = (u16*)p;    p += MDl * 2;
    u16*   QKVb = (u16*)p;
    u16*   FFb  = QKVb;
    u16*   T1   = QKVb;
    u16*   T2   = QKVb + MDl;
    float* LNout= (float*)QKVb;
    p += (long)MM * 1536 * 2;
    u16*   Ob   = (u16*)p;    p += MDl * 2;
    u16*   Xbf  = (u16*)p;    p += MDl * 2;
    u16*   WqkvT= (u16*)p;    p += 4L * 1536 * 512 * 2;
    u16*   WoT  = (u16*)p;    p += 4L * 512 * 512 * 2;
    u16*   W1T  = (u16*)p;    p += 4L * 2048 * 512 * 2;
    u16*   W2T  = (u16*)p;    p += 4L * 512 * 2048 * 2;
    u16*   WhT  = (u16*)p;    p += 3L * 512 * 512 * 2;
    float* bqkv = (float*)p;  p += 4L * 1536 * 4;
    float* XM   = (float*)p;  p += (long)BS * DD * 4;

    dim3 blk(256);

    WTbl tbl;
    for (int l = 0; l < 4; ++l) {
        tbl.e[l * 4 + 0] = {Wq + (long)l * 262144, WqkvT + (long)l * 786432};
        tbl.e[l * 4 + 1] = {Wk + (long)l * 262144, WqkvT + (long)l * 786432 + 262144};
        tbl.e[l * 4 + 2] = {Wv + (long)l * 262144, WqkvT + (long)l * 786432 + 524288};
        tbl.e[l * 4 + 3] = {Wo + (long)l * 262144, WoT + (long)l * 262144};
    }
    tbl.e[16] = {heavy_w,  WhT};
    tbl.e[17] = {heavy_a1, WhT + 262144};
    tbl.e[18] = {heavy_a2, WhT + 524288};
    wprep512_kernel<<<dim3(16, 16, 19), blk, 0, stream>>>(tbl);
    wprep_kernel<<<dim3(64, 16, 4), blk, 0, stream>>>(W1, W1T,  512, 2048, 1048576, 1048576);
    wprep_kernel<<<dim3(16, 64, 4), blk, 0, stream>>>(W2, W2T, 2048,  512, 1048576, 1048576);
    bprep_kernel<<<24, blk, 0, stream>>>(bq, bk, bv, bqkv);

    embed_kernel<<<MM * DD / 256, blk, 0, stream>>>(tokens, emb, X);

    dim3 gQKV(12, 64), g512(4, 64), gFF1(16, 64);

    for (int l = 0; l < LL; ++l) {
        ln_kernel<1><<<MM, blk, 0, stream>>>(X, Hh, ln1_g + l * DD, ln1_b + l * DD);
        mfma_gemm<1, 1, 0, 0><<<gQKV, blk, 0, stream>>>(
            Hh, WqkvT + (long)l * 786432, bqkv + l * 1536, nullptr, QKVb, 1536, 512);
        attn_kernel<<<dim3(8, HH, BS), blk, 0, stream>>>(QKVb, Ob);
        mfma_gemm<0, 1, 0, 1><<<g512, blk, 0, stream>>>(
            Ob, WoT + (long)l * 262144, bo + l * DD, X, X, 512, 512);
        ln_kernel<1><<<MM, blk, 0, stream>>>(X, Hh, ln2_g + l * DD, ln2_b + l * DD);
        mfma_gemm<1, 1, 1, 0><<<gFF1, blk, 0, stream>>>(
            Hh, W1T + (long)l * 1048576, b1 + l * FFD, nullptr, FFb, 2048, 512);
        mfma_gemm<0, 1, 0, 1><<<g512, blk, 0, stream>>>(
            FFb, W2T + (long)l * 1048576, b2 + l * DD, X, X, 512, 2048);
    }

    f2b_kernel<<<MM * DD / 256, blk, 0, stream>>>(X, Xbf, MM * DD);
    mfma_gemm<1, 0, 0, 0><<<g512, blk, 0, stream>>>(Xbf, WhT,          nullptr, nullptr, T1, 512, 512);
    mfma_gemm<1, 0, 0, 0><<<g512, blk, 0, stream>>>(T1,  WhT + 262144, nullptr, nullptr, T2, 512, 512);
    mfma_gemm<0, 1, 2, 0><<<g512, blk, 0, stream>>>(T2,  WhT + 524288, heavy_b, nullptr, X,  512, 512);

    ln_kernel<0><<<MM, blk, 0, stream>>>(X, LNout, norm_g, norm_b);
    zero_kernel<<<(BS * DD + 255) / 256, blk, 0, stream>>>(XM, BS * DD);
    colmean_kernel<<<256, blk, 0, stream>>>(LNout, XM);
    cls_kernel<<<BS, blk, 0, stream>>>(XM, cls_W, cls_b, out);
}

// Round 6
// 898.961 us; speedup vs baseline: 1.5604x; 1.5604x over previous
//
#include <hip/hip_runtime.h>
#include <math.h>

#define BS   8
#define TT   1024
#define DD   512
#define HH   8
#define LL   4
#define FFD  2048
#define NCC  10
#define MM   (BS*TT)
#define MDl  ((long)MM*DD)

typedef unsigned short u16;
typedef short  short8 __attribute__((ext_vector_type(8)));
typedef float  f32x4  __attribute__((ext_vector_type(4)));
typedef u16    u16x8  __attribute__((ext_vector_type(8)));
typedef u16    u16x4  __attribute__((ext_vector_type(4)));

static __device__ __forceinline__ u16 f2b(float f) {
    union { float f; unsigned u; } x; x.f = f;
    unsigned r = x.u + 0x7FFFu + ((x.u >> 16) & 1u);   // RNE
    return (u16)(r >> 16);
}
// round-half-up: 2 insts, differs from RNE only on exact ties (negligible)
static __device__ __forceinline__ u16 f2b_fast(float f) {
    union { float f; unsigned u; } x; x.f = f;
    return (u16)((x.u + 0x8000u) >> 16);
}
static __device__ __forceinline__ float b2f(u16 u) {
    union { unsigned u; float f; } x; x.u = ((unsigned)u) << 16;
    return x.f;
}

// ---------------------------------------------------------------------------
// Embedding + sinusoidal positional encoding  (X fp32)
// ---------------------------------------------------------------------------
__global__ __launch_bounds__(256)
void embed_kernel(const int* __restrict__ tok, const float* __restrict__ emb,
                  float* __restrict__ X) {
    int i = blockIdx.x * 256 + threadIdx.x;
    int d = i & (DD - 1);
    int row = i >> 9;
    int t = row & (TT - 1);
    int j = d >> 1;
    float freq = __expf((float)(2 * j) * (-9.210340371976184f / 512.0f));
    float ang = (float)t * freq;
    float pe = (d & 1) ? cosf(ang) : sinf(ang);
    X[i] = emb[(long)tok[row] * DD + d] + pe;
}

// ---------------------------------------------------------------------------
// LayerNorm over D=512; OUTBF: 1 -> bf16 out, 0 -> fp32 out
// ---------------------------------------------------------------------------
template<int OUTBF>
__global__ __launch_bounds__(256)
void ln_kernel(const float* __restrict__ in, void* __restrict__ outp,
               const float* __restrict__ g, const float* __restrict__ b) {
    int row = blockIdx.x;
    int tid = threadIdx.x;
    const float* x = in + (long)row * DD;
    float x1 = x[tid], x2 = x[tid + 256];
    __shared__ float red[256], red2[256];
    red[tid] = x1 + x2;
    red2[tid] = x1 * x1 + x2 * x2;
    __syncthreads();
    for (int st = 128; st > 0; st >>= 1) {
        if (tid < st) { red[tid] += red[tid + st]; red2[tid] += red2[tid + st]; }
        __syncthreads();
    }
    float mean = red[0] * (1.0f / DD);
    float var = red2[0] * (1.0f / DD) - mean * mean;
    float rstd = rsqrtf(var + 1e-5f);
    float y1 = (x1 - mean) * rstd * g[tid] + b[tid];
    float y2 = (x2 - mean) * rstd * g[tid + 256] + b[tid + 256];
    if (OUTBF) {
        u16* o = (u16*)outp + (long)row * DD;
        o[tid] = f2b(y1); o[tid + 256] = f2b(y2);
    } else {
        float* o = (float*)outp + (long)row * DD;
        o[tid] = y1; o[tid + 256] = y2;
    }
}

// ---------------------------------------------------------------------------
// bf16 MFMA GEMM: C[M=8192, N] = epi(A[M,K] @ W), W given as WT[N][K] bf16.
// 128x128 tile, BK=64, 256 thr. Register-prefetch pipeline (R5, kept: non-attn
// total improved 799->670 us). LDS chunk c of row r at slot c^(r&7).
// ---------------------------------------------------------------------------
template<int OUTBF, int HAS_BIAS, int ACT, int HAS_RES>
__global__ __launch_bounds__(256, 2)
void mfma_gemm(const u16* __restrict__ A, const u16* __restrict__ BT,
               const float* __restrict__ bias, const float* __restrict__ R,
               void* __restrict__ Cout, int N, int K) {
    __shared__ __align__(16) u16 lds[17408];   // As(8192)+Bs(8192) | Cs(128x136)
    u16* As = lds;
    u16* Bs = lds + 8192;
    const int tid = threadIdx.x;
    const int lane = tid & 63;
    const int w = tid >> 6;
    const long bm = (long)blockIdx.y * 128;
    const long bn = (long)blockIdx.x * 128;

    f32x4 acc[4][4];
#pragma unroll
    for (int i = 0; i < 4; ++i)
#pragma unroll
        for (int j = 0; j < 4; ++j) acc[i][j] = {0.f, 0.f, 0.f, 0.f};

    const int srow = tid >> 1;
    const int sc0 = (tid & 1) * 4;
    const u16* Ag = A + (bm + srow) * K + sc0 * 8;
    const u16* Bg = BT + (bn + srow) * K + sc0 * 8;
    int soff[4];
#pragma unroll
    for (int j = 0; j < 4; ++j)
        soff[j] = srow * 64 + ((sc0 + j) ^ (srow & 7)) * 8;

    const int fr = lane & 15;
    const int g = lane >> 4;
    const int am0 = (w >> 1) * 64 + fr;
    const int bn0 = (w & 1) * 64 + fr;
    const int sw = fr & 7;

    u16x8 sa[2][4], sb[2][4];
#pragma unroll
    for (int j = 0; j < 4; ++j) {          // prologue: tile k0=0 -> regs
        sa[0][j] = *(const u16x8*)(Ag + j * 8);
        sb[0][j] = *(const u16x8*)(Bg + j * 8);
    }

    for (int k0 = 0; k0 < K; k0 += 128) {
#pragma unroll
        for (int half = 0; half < 2; ++half) {
            const int cb = half, nb = half ^ 1;
            __syncthreads();               // prior frag reads done
#pragma unroll
            for (int j = 0; j < 4; ++j) {
                *(u16x8*)&As[soff[j]] = sa[cb][j];
                *(u16x8*)&Bs[soff[j]] = sb[cb][j];
            }
            const int knext = k0 + (half + 1) * 64;
            if (knext < K) {               // prefetch next tile -> regs
#pragma unroll
                for (int j = 0; j < 4; ++j) {
                    sa[nb][j] = *(const u16x8*)(Ag + knext + j * 8);
                    sb[nb][j] = *(const u16x8*)(Bg + knext + j * 8);
                }
            }
            __syncthreads();               // staged tile visible
#pragma unroll
            for (int kk = 0; kk < 2; ++kk) {
                const int pos = ((kk << 2) + g) ^ sw;
                short8 af[4], bfv[4];
#pragma unroll
                for (int mi = 0; mi < 4; ++mi)
                    af[mi] = *(const short8*)&As[(am0 + mi * 16) * 64 + pos * 8];
#pragma unroll
                for (int ni = 0; ni < 4; ++ni)
                    bfv[ni] = *(const short8*)&Bs[(bn0 + ni * 16) * 64 + pos * 8];
#pragma unroll
                for (int mi = 0; mi < 4; ++mi)
#pragma unroll
                    for (int ni = 0; ni < 4; ++ni)
                        acc[mi][ni] = __builtin_amdgcn_mfma_f32_16x16x32_bf16(
                            af[mi], bfv[ni], acc[mi][ni], 0, 0, 0);
            }
        }
    }

    // C/D layout: col = lane&15, row = (lane>>4)*4 + reg
    const int erow0 = (w >> 1) * 64 + g * 4;
    const int ecol0 = (w & 1) * 64 + fr;

    if (OUTBF) {
        __syncthreads();
#pragma unroll
        for (int ni = 0; ni < 4; ++ni) {
            const long col = bn + ecol0 + ni * 16;
            float bv = 0.f;
            if (HAS_BIAS) bv = bias[col];
#pragma unroll
            for (int mi = 0; mi < 4; ++mi)
#pragma unroll
                for (int r = 0; r < 4; ++r) {
                    const int row = erow0 + mi * 16 + r;
                    float v = acc[mi][ni][r];
                    if (HAS_BIAS) v += bv;
                    if (ACT == 1) v = 0.5f * v * (1.0f + erff(v * 0.70710678118654752f));
                    if (ACT == 2) v = tanhf(v);
                    if (HAS_RES) v += R[(bm + row) * N + col];
                    lds[row * 136 + ecol0 + ni * 16] = f2b(v);
                }
        }
        __syncthreads();
        const int srow2 = tid >> 4;
        const int sch2 = tid & 15;
        u16* Cp = (u16*)Cout;
#pragma unroll
        for (int rr = 0; rr < 8; ++rr) {
            const int row = srow2 + rr * 16;
            u16x8 vv = *(const u16x8*)&lds[row * 136 + sch2 * 8];
            *(u16x8*)(Cp + (bm + row) * N + bn + sch2 * 8) = vv;
        }
    } else {
#pragma unroll
        for (int ni = 0; ni < 4; ++ni) {
            const long col = bn + ecol0 + ni * 16;
            float bv = 0.f;
            if (HAS_BIAS) bv = bias[col];
#pragma unroll
            for (int mi = 0; mi < 4; ++mi)
#pragma unroll
                for (int r = 0; r < 4; ++r) {
                    const long row = bm + erow0 + mi * 16 + r;
                    float v = acc[mi][ni][r];
                    if (HAS_BIAS) v += bv;
                    if (ACT == 1) v = 0.5f * v * (1.0f + erff(v * 0.70710678118654752f));
                    if (ACT == 2) v = tanhf(v);
                    if (HAS_RES) v += R[row * N + col];
                    ((float*)Cout)[row * N + col] = v;
                }
        }
    }
}

// ---------------------------------------------------------------------------
// MFMA flash attention, register-prefetch pipeline, manual 2-phase kt-loop
// (#pragma unroll 1 + static A/B buffer sets: no multi-tile load hoisting,
// no dynamic register indexing -> no spill; R5's full unroll spilled to
// scratch: WRITE_SIZE 8->172 MB).
// ---------------------------------------------------------------------------
__global__ __launch_bounds__(256, 2)
void attn_kernel(const u16* __restrict__ QKV, u16* __restrict__ O) {
    const int qblk = blockIdx.x;
    const int h = blockIdx.y;
    const int b = blockIdx.z;
    const int tid = threadIdx.x;
    const int lane = tid & 63;
    const int w = tid >> 6;
    const int fr = lane & 15;
    const int g = lane >> 4;
    const int q8 = g * 8;

    __shared__ __align__(16) u16 Ks[64 * 64];     // [key][64d] swizzled
    __shared__ __align__(16) u16 Vt[64 * 72];     // [d][key] padded
    __shared__ __align__(16) u16 Pw[4][32 * 72];  // per-wave P[q][key]

    const long rowb = (long)b * TT;
    const int wq0 = qblk * 128 + w * 32;

    // Q A-frags (once)
    short8 qf[2][2];
#pragma unroll
    for (int qt = 0; qt < 2; ++qt)
#pragma unroll
        for (int hf = 0; hf < 2; ++hf)
            qf[qt][hf] = *(const short8*)(QKV + (rowb + wq0 + qt * 16 + fr) * 1536
                                          + h * 64 + hf * 32 + q8);

    f32x4 accO[2][4];
    float lsum[2][4];
#pragma unroll
    for (int qt = 0; qt < 2; ++qt) {
#pragma unroll
        for (int nt = 0; nt < 4; ++nt) accO[qt][nt] = {0.f, 0.f, 0.f, 0.f};
#pragma unroll
        for (int r = 0; r < 4; ++r) lsum[qt][r] = 0.f;
    }

    // staging assignments
    const int skey = tid >> 2;              // 0..63
    const int skc = (tid & 3) * 2;          // chunks skc, skc+1
    const int koff0 = skey * 64 + ((skc ^ (skey & 7)) * 8);
    const int koff1 = skey * 64 + (((skc + 1) ^ (skey & 7)) * 8);
    const int vkp = tid & 31;               // keys 2vkp, 2vkp+1
    const int vd0 = (tid >> 5) * 8;         // 8 d values

    auto load_kv = [&](int kt_, u16x8* kr_, u16x8* vr_) {
        const long tb_ = (rowb + (long)kt_ * 64) * 1536 + h * 64;
        const u16* kp_ = QKV + tb_ + 512 + (long)skey * 1536 + skc * 8;
        kr_[0] = *(const u16x8*)kp_;
        kr_[1] = *(const u16x8*)(kp_ + 8);
        const u16* vp_ = QKV + tb_ + 1024 + (long)(vkp * 2) * 1536 + vd0;
        vr_[0] = *(const u16x8*)vp_;
        vr_[1] = *(const u16x8*)(vp_ + 1536);
    };
    auto stage = [&](u16x8* kr_, u16x8* vr_) {
        *(u16x8*)&Ks[koff0] = kr_[0];
        *(u16x8*)&Ks[koff1] = kr_[1];
        unsigned* Vt32 = (unsigned*)Vt;
#pragma unroll
        for (int j = 0; j < 8; ++j)
            Vt32[(vd0 + j) * 36 + vkp] =
                (unsigned)vr_[0][j] | ((unsigned)vr_[1][j] << 16);
    };
    auto compute = [&]() {
        f32x4 accS[2][4];
#pragma unroll
        for (int qt = 0; qt < 2; ++qt)
#pragma unroll
            for (int n = 0; n < 4; ++n) accS[qt][n] = {0.f, 0.f, 0.f, 0.f};
#pragma unroll
        for (int n = 0; n < 4; ++n)
#pragma unroll
            for (int hf = 0; hf < 2; ++hf) {
                short8 bk = *(const short8*)&Ks[(n * 16 + fr) * 64
                                                + ((((hf << 2) + g) ^ (fr & 7)) * 8)];
                accS[0][n] = __builtin_amdgcn_mfma_f32_16x16x32_bf16(qf[0][hf], bk, accS[0][n], 0, 0, 0);
                accS[1][n] = __builtin_amdgcn_mfma_f32_16x16x32_bf16(qf[1][hf], bk, accS[1][n], 0, 0, 0);
            }
#pragma unroll
        for (int qt = 0; qt < 2; ++qt)
#pragma unroll
            for (int r = 0; r < 4; ++r) {
                int prow = qt * 16 + g * 4 + r;
#pragma unroll
                for (int n = 0; n < 4; ++n) {
                    float pv = exp2f(accS[qt][n][r] * 0.18033688011112042f);
                    lsum[qt][r] += pv;
                    Pw[w][prow * 72 + n * 16 + fr] = f2b_fast(pv);
                }
            }
#pragma unroll
        for (int hf = 0; hf < 2; ++hf) {
            short8 pa0 = *(const short8*)&Pw[w][fr * 72 + hf * 32 + q8];
            short8 pa1 = *(const short8*)&Pw[w][(16 + fr) * 72 + hf * 32 + q8];
#pragma unroll
            for (int nt = 0; nt < 4; ++nt) {
                short8 bv = *(const short8*)&Vt[(nt * 16 + fr) * 72 + hf * 32 + q8];
                accO[0][nt] = __builtin_amdgcn_mfma_f32_16x16x32_bf16(pa0, bv, accO[0][nt], 0, 0, 0);
                accO[1][nt] = __builtin_amdgcn_mfma_f32_16x16x32_bf16(pa1, bv, accO[1][nt], 0, 0, 0);
            }
        }
    };

    u16x8 krA[2], vrA[2], krB[2], vrB[2];
    load_kv(0, krA, vrA);

#pragma unroll 1
    for (int kt = 0; kt < 16; kt += 2) {
        __syncthreads();                    // prior tile fully consumed
        stage(krA, vrA);
        load_kv(kt + 1, krB, vrB);          // in flight through compute(kt)
        __syncthreads();                    // staged tile visible
        compute();
        __syncthreads();
        stage(krB, vrB);
        if (kt + 2 < 16) load_kv(kt + 2, krA, vrA);
        __syncthreads();
        compute();
    }

#pragma unroll
    for (int qt = 0; qt < 2; ++qt)
#pragma unroll
        for (int r = 0; r < 4; ++r) {
            float s = lsum[qt][r];
            s += __shfl_xor(s, 1, 64);
            s += __shfl_xor(s, 2, 64);
            s += __shfl_xor(s, 4, 64);
            s += __shfl_xor(s, 8, 64);
            lsum[qt][r] = 1.0f / s;
        }
#pragma unroll
    for (int qt = 0; qt < 2; ++qt)
#pragma unroll
        for (int nt = 0; nt < 4; ++nt)
#pragma unroll
            for (int r = 0; r < 4; ++r) {
                long row = rowb + wq0 + qt * 16 + g * 4 + r;
                O[row * DD + h * 64 + nt * 16 + fr] = f2b(accO[qt][nt][r] * lsum[qt][r]);
            }
}

// ---------------------------------------------------------------------------
// Weight prep. wprep512_kernel: nineteen 512x512 transposes via pointer table.
// ---------------------------------------------------------------------------
struct WP   { const float* s; u16* d; };
struct WTbl { WP e[19]; };

__global__ __launch_bounds__(256)
void wprep512_kernel(WTbl tbl) {
    const float* src = tbl.e[blockIdx.z].s;
    u16* dst = tbl.e[blockIdx.z].d;
    int k0 = blockIdx.y * 32, n0 = blockIdx.x * 32;
    __shared__ float tile[32][33];
    int tx = threadIdx.x & 31, ty = threadIdx.x >> 5;
#pragma unroll
    for (int i = 0; i < 4; ++i)
        tile[ty + 8 * i][tx] = src[(long)(k0 + ty + 8 * i) * 512 + n0 + tx];
    __syncthreads();
#pragma unroll
    for (int i = 0; i < 4; ++i) {
        int r = ty + 8 * i;
        dst[(long)(n0 + r) * 512 + k0 + tx] = f2b(tile[tx][r]);
    }
}

__global__ __launch_bounds__(256)
void wprep_kernel(const float* __restrict__ src, u16* __restrict__ dst,
                  int K, int N, long srcLS, long dstLS) {
    int l = blockIdx.z;
    src += (long)l * srcLS;
    dst += (long)l * dstLS;
    int k0 = blockIdx.y * 32, n0 = blockIdx.x * 32;
    __shared__ float tile[32][33];
    int tx = threadIdx.x & 31, ty = threadIdx.x >> 5;
#pragma unroll
    for (int i = 0; i < 4; ++i)
        tile[ty + 8 * i][tx] = src[(long)(k0 + ty + 8 * i) * N + n0 + tx];
    __syncthreads();
#pragma unroll
    for (int i = 0; i < 4; ++i) {
        int r = ty + 8 * i;
        dst[(long)(n0 + r) * K + k0 + tx] = f2b(tile[tx][r]);
    }
}

__global__ __launch_bounds__(256)
void bprep_kernel(const float* __restrict__ bq, const float* __restrict__ bk,
                  const float* __restrict__ bv, float* __restrict__ dst) {
    int i = blockIdx.x * 256 + threadIdx.x;
    int l = i / 1536, j = i - l * 1536;
    float v = (j < 512) ? bq[l * 512 + j]
            : (j < 1024) ? bk[l * 512 + j - 512]
                         : bv[l * 512 + j - 1024];
    dst[i] = v;
}

__global__ __launch_bounds__(256)
void f2b_kernel(const float* __restrict__ in, u16* __restrict__ out, int n) {
    int i = blockIdx.x * 256 + threadIdx.x;
    if (i < n) out[i] = f2b(in[i]);
}

__global__ __launch_bounds__(256)
void zero_kernel(float* __restrict__ p, int n) {
    int i = blockIdx.x * 256 + threadIdx.x;
    if (i < n) p[i] = 0.0f;
}

__global__ __launch_bounds__(256)
void colmean_kernel(const float* __restrict__ Hn, float* __restrict__ XM) {
    int blk = blockIdx.x;
    int b = blk >> 5;
    int r0 = (blk & 31) * 32;
    int tid = threadIdx.x;
    float acc0 = 0.0f, acc1 = 0.0f;
    for (int r = 0; r < 32; ++r) {
        long off = ((long)b * TT + r0 + r) * DD + tid;
        acc0 += Hn[off];
        acc1 += Hn[off + 256];
    }
    atomicAdd(&XM[b * DD + tid], acc0);
    atomicAdd(&XM[b * DD + tid + 256], acc1);
}

__global__ __launch_bounds__(256)
void cls_kernel(const float* __restrict__ XM, const float* __restrict__ W,
                const float* __restrict__ bias, float* __restrict__ out) {
    int b = blockIdx.x;
    int tid = threadIdx.x;
    __shared__ float xm[DD];
    xm[tid] = XM[b * DD + tid] * (1.0f / TT);
    xm[tid + 256] = XM[b * DD + tid + 256] * (1.0f / TT);
    __syncthreads();
    if (tid < NCC) {
        float s = bias[tid];
        for (int d = 0; d < DD; ++d) s += xm[d] * W[d * NCC + tid];
        out[b * NCC + tid] = s;
    }
}

// ---------------------------------------------------------------------------
extern "C" void kernel_launch(void* const* d_in, const int* in_sizes, int n_in,
                              void* d_out, int out_size, void* d_ws, size_t ws_size,
                              hipStream_t stream) {
    const int*   tokens  = (const int*)d_in[0];
    const float* emb     = (const float*)d_in[1];
    const float* Wq      = (const float*)d_in[2];
    const float* bq      = (const float*)d_in[3];
    const float* Wk      = (const float*)d_in[4];
    const float* bk      = (const float*)d_in[5];
    const float* Wv      = (const float*)d_in[6];
    const float* bv      = (const float*)d_in[7];
    const float* Wo      = (const float*)d_in[8];
    const float* bo      = (const float*)d_in[9];
    const float* ln1_g   = (const float*)d_in[10];
    const float* ln1_b   = (const float*)d_in[11];
    const float* ln2_g   = (const float*)d_in[12];
    const float* ln2_b   = (const float*)d_in[13];
    const float* W1      = (const float*)d_in[14];
    const float* b1      = (const float*)d_in[15];
    const float* W2      = (const float*)d_in[16];
    const float* b2      = (const float*)d_in[17];
    const float* heavy_w = (const float*)d_in[18];
    const float* heavy_b = (const float*)d_in[19];
    const float* heavy_a1= (const float*)d_in[20];
    const float* heavy_a2= (const float*)d_in[21];
    const float* norm_g  = (const float*)d_in[22];
    const float* norm_b  = (const float*)d_in[23];
    const float* cls_W   = (const float*)d_in[24];
    const float* cls_b   = (const float*)d_in[25];
    float* out = (float*)d_out;

    char* p = (char*)d_ws;
    float* X    = (float*)p;  p += MDl * 4;
    u16*   Hh   = (u16*)p;    p += MDl * 2;
    u16*   QKVb = (u16*)p;
    u16*   FFb  = QKVb;
    u16*   T1   = QKVb;
    u16*   T2   = QKVb + MDl;
    float* LNout= (float*)QKVb;
    p += (long)MM * 1536 * 2;
    u16*   Ob   = (u16*)p;    p += MDl * 2;
    u16*   Xbf  = (u16*)p;    p += MDl * 2;
    u16*   WqkvT= (u16*)p;    p += 4L * 1536 * 512 * 2;
    u16*   WoT  = (u16*)p;    p += 4L * 512 * 512 * 2;
    u16*   W1T  = (u16*)p;    p += 4L * 2048 * 512 * 2;
    u16*   W2T  = (u16*)p;    p += 4L * 512 * 2048 * 2;
    u16*   WhT  = (u16*)p;    p += 3L * 512 * 512 * 2;
    float* bqkv = (float*)p;  p += 4L * 1536 * 4;
    float* XM   = (float*)p;  p += (long)BS * DD * 4;

    dim3 blk(256);

    WTbl tbl;
    for (int l = 0; l < 4; ++l) {
        tbl.e[l * 4 + 0] = {Wq + (long)l * 262144, WqkvT + (long)l * 786432};
        tbl.e[l * 4 + 1] = {Wk + (long)l * 262144, WqkvT + (long)l * 786432 + 262144};
        tbl.e[l * 4 + 2] = {Wv + (long)l * 262144, WqkvT + (long)l * 786432 + 524288};
        tbl.e[l * 4 + 3] = {Wo + (long)l * 262144, WoT + (long)l * 262144};
    }
    tbl.e[16] = {heavy_w,  WhT};
    tbl.e[17] = {heavy_a1, WhT + 262144};
    tbl.e[18] = {heavy_a2, WhT + 524288};
    wprep512_kernel<<<dim3(16, 16, 19), blk, 0, stream>>>(tbl);
    wprep_kernel<<<dim3(64, 16, 4), blk, 0, stream>>>(W1, W1T,  512, 2048, 1048576, 1048576);
    wprep_kernel<<<dim3(16, 64, 4), blk, 0, stream>>>(W2, W2T, 2048,  512, 1048576, 1048576);
    bprep_kernel<<<24, blk, 0, stream>>>(bq, bk, bv, bqkv);

    embed_kernel<<<MM * DD / 256, blk, 0, stream>>>(tokens, emb, X);

    dim3 gQKV(12, 64), g512(4, 64), gFF1(16, 64);

    for (int l = 0; l < LL; ++l) {
        ln_kernel<1><<<MM, blk, 0, stream>>>(X, Hh, ln1_g + l * DD, ln1_b + l * DD);
        mfma_gemm<1, 1, 0, 0><<<gQKV, blk, 0, stream>>>(
            Hh, WqkvT + (long)l * 786432, bqkv + l * 1536, nullptr, QKVb, 1536, 512);
        attn_kernel<<<dim3(8, HH, BS), blk, 0, stream>>>(QKVb, Ob);
        mfma_gemm<0, 1, 0, 1><<<g512, blk, 0, stream>>>(
            Ob, WoT + (long)l * 262144, bo + l * DD, X, X, 512, 512);
        ln_kernel<1><<<MM, blk, 0, stream>>>(X, Hh, ln2_g + l * DD, ln2_b + l * DD);
        mfma_gemm<1, 1, 1, 0><<<gFF1, blk, 0, stream>>>(
            Hh, W1T + (long)l * 1048576, b1 + l * FFD, nullptr, FFb, 2048, 512);
        mfma_gemm<0, 1, 0, 1><<<g512, blk, 0, stream>>>(
            FFb, W2T + (long)l * 1048576, b2 + l * DD, X, X, 512, 2048);
    }

    f2b_kernel<<<MM * DD / 256, blk, 0, stream>>>(X, Xbf, MM * DD);
    mfma_gemm<1, 0, 0, 0><<<g512, blk, 0, stream>>>(Xbf, WhT,          nullptr, nullptr, T1, 512, 512);
    mfma_gemm<1, 0, 0, 0><<<g512, blk, 0, stream>>>(T1,  WhT + 262144, nullptr, nullptr, T2, 512, 512);
    mfma_gemm<0, 1, 2, 0><<<g512, blk, 0, stream>>>(T2,  WhT + 524288, heavy_b, nullptr, X,  512, 512);

    ln_kernel<0><<<MM, blk, 0, stream>>>(X, LNout, norm_g, norm_b);
    zero_kernel<<<(BS * DD + 255) / 256, blk, 0, stream>>>(XM, BS * DD);
    colmean_kernel<<<256, blk, 0, stream>>>(LNout, XM);
    cls_kernel<<<BS, blk, 0, stream>>>(XM, cls_W, cls_b, out);
}

// Round 7
// 829.519 us; speedup vs baseline: 1.6910x; 1.0837x over previous
//
#include <hip/hip_runtime.h>
#include <math.h>

#define BS   8
#define TT   1024
#define DD   512
#define HH   8
#define LL   4
#define FFD  2048
#define NCC  10
#define MM   (BS*TT)
#define MDl  ((long)MM*DD)

typedef unsigned short u16;
typedef short  short8 __attribute__((ext_vector_type(8)));
typedef float  f32x4  __attribute__((ext_vector_type(4)));
typedef u16    u16x8  __attribute__((ext_vector_type(8)));
typedef u16    u16x4  __attribute__((ext_vector_type(4)));

static __device__ __forceinline__ u16 f2b(float f) {
    union { float f; unsigned u; } x; x.f = f;
    unsigned r = x.u + 0x7FFFu + ((x.u >> 16) & 1u);   // RNE
    return (u16)(r >> 16);
}
// round-half-up: 2 insts, differs from RNE only on exact ties (negligible)
static __device__ __forceinline__ u16 f2b_fast(float f) {
    union { float f; unsigned u; } x; x.f = f;
    return (u16)((x.u + 0x8000u) >> 16);
}
static __device__ __forceinline__ float b2f(u16 u) {
    union { unsigned u; float f; } x; x.u = ((unsigned)u) << 16;
    return x.f;
}

// ---------------------------------------------------------------------------
// Embedding + sinusoidal positional encoding  (X fp32)
// ---------------------------------------------------------------------------
__global__ __launch_bounds__(256)
void embed_kernel(const int* __restrict__ tok, const float* __restrict__ emb,
                  float* __restrict__ X) {
    int i = blockIdx.x * 256 + threadIdx.x;
    int d = i & (DD - 1);
    int row = i >> 9;
    int t = row & (TT - 1);
    int j = d >> 1;
    float freq = __expf((float)(2 * j) * (-9.210340371976184f / 512.0f));
    float ang = (float)t * freq;
    float pe = (d & 1) ? cosf(ang) : sinf(ang);
    X[i] = emb[(long)tok[row] * DD + d] + pe;
}

// ---------------------------------------------------------------------------
// LayerNorm over D=512; OUTBF: 1 -> bf16 out, 0 -> fp32 out
// ---------------------------------------------------------------------------
template<int OUTBF>
__global__ __launch_bounds__(256)
void ln_kernel(const float* __restrict__ in, void* __restrict__ outp,
               const float* __restrict__ g, const float* __restrict__ b) {
    int row = blockIdx.x;
    int tid = threadIdx.x;
    const float* x = in + (long)row * DD;
    float x1 = x[tid], x2 = x[tid + 256];
    __shared__ float red[256], red2[256];
    red[tid] = x1 + x2;
    red2[tid] = x1 * x1 + x2 * x2;
    __syncthreads();
    for (int st = 128; st > 0; st >>= 1) {
        if (tid < st) { red[tid] += red[tid + st]; red2[tid] += red2[tid + st]; }
        __syncthreads();
    }
    float mean = red[0] * (1.0f / DD);
    float var = red2[0] * (1.0f / DD) - mean * mean;
    float rstd = rsqrtf(var + 1e-5f);
    float y1 = (x1 - mean) * rstd * g[tid] + b[tid];
    float y2 = (x2 - mean) * rstd * g[tid + 256] + b[tid + 256];
    if (OUTBF) {
        u16* o = (u16*)outp + (long)row * DD;
        o[tid] = f2b(y1); o[tid + 256] = f2b(y2);
    } else {
        float* o = (float*)outp + (long)row * DD;
        o[tid] = y1; o[tid + 256] = y2;
    }
}

// ---------------------------------------------------------------------------
// bf16 MFMA GEMM: C[M=8192, N] = epi(A[M,K] @ W), W given as WT[N][K] bf16.
// 128x128 tile, BK=64, **512 threads (8 waves)**: wave (w>>1, w&1) computes a
// 32x64 sub-tile (2x4 MFMAs). Doubles waves/CU for the 1-block/CU N=512
// dispatches that were latency-starved at 4 waves/CU. Register-prefetch
// pipeline (R5, proven). LDS chunk c of row r at slot c^(r&7).
// ---------------------------------------------------------------------------
template<int OUTBF, int HAS_BIAS, int ACT, int HAS_RES>
__global__ __launch_bounds__(512, 2)
void mfma_gemm(const u16* __restrict__ A, const u16* __restrict__ BT,
               const float* __restrict__ bias, const float* __restrict__ R,
               void* __restrict__ Cout, int N, int K) {
    __shared__ __align__(16) u16 lds[17408];   // As(8192)+Bs(8192) | Cs(128x136)
    u16* As = lds;
    u16* Bs = lds + 8192;
    const int tid = threadIdx.x;
    const int lane = tid & 63;
    const int w = tid >> 6;                    // 0..7
    const int wm = w >> 1;                     // 0..3: rows [wm*32, wm*32+32)
    const int wn = w & 1;                      // 0..1: cols [wn*64, wn*64+64)
    const long bm = (long)blockIdx.y * 128;
    const long bn = (long)blockIdx.x * 128;

    f32x4 acc[2][4];
#pragma unroll
    for (int i = 0; i < 2; ++i)
#pragma unroll
        for (int j = 0; j < 4; ++j) acc[i][j] = {0.f, 0.f, 0.f, 0.f};

    // staging: thread -> row tid>>2 (0..127), chunks (tid&3)*2 + {0,1}
    const int srow = tid >> 2;
    const int sc0 = (tid & 3) * 2;
    const u16* Ag = A + (bm + srow) * K + sc0 * 8;
    const u16* Bg = BT + (bn + srow) * K + sc0 * 8;
    int soff[2];
#pragma unroll
    for (int j = 0; j < 2; ++j)
        soff[j] = srow * 64 + ((sc0 + j) ^ (srow & 7)) * 8;

    const int fr = lane & 15;
    const int g = lane >> 4;
    const int am0 = wm * 32 + fr;
    const int bn0 = wn * 64 + fr;
    const int sw = fr & 7;

    u16x8 sa[2][2], sb[2][2];
#pragma unroll
    for (int j = 0; j < 2; ++j) {          // prologue: tile k0=0 -> regs
        sa[0][j] = *(const u16x8*)(Ag + j * 8);
        sb[0][j] = *(const u16x8*)(Bg + j * 8);
    }

    for (int k0 = 0; k0 < K; k0 += 128) {
#pragma unroll
        for (int half = 0; half < 2; ++half) {
            const int cb = half, nb = half ^ 1;
            __syncthreads();               // prior frag reads done
#pragma unroll
            for (int j = 0; j < 2; ++j) {
                *(u16x8*)&As[soff[j]] = sa[cb][j];
                *(u16x8*)&Bs[soff[j]] = sb[cb][j];
            }
            const int knext = k0 + (half + 1) * 64;
            if (knext < K) {               // prefetch next tile -> regs
#pragma unroll
                for (int j = 0; j < 2; ++j) {
                    sa[nb][j] = *(const u16x8*)(Ag + knext + j * 8);
                    sb[nb][j] = *(const u16x8*)(Bg + knext + j * 8);
                }
            }
            __syncthreads();               // staged tile visible
#pragma unroll
            for (int kk = 0; kk < 2; ++kk) {
                const int pos = ((kk << 2) + g) ^ sw;
                short8 af[2], bfv[4];
#pragma unroll
                for (int mi = 0; mi < 2; ++mi)
                    af[mi] = *(const short8*)&As[(am0 + mi * 16) * 64 + pos * 8];
#pragma unroll
                for (int ni = 0; ni < 4; ++ni)
                    bfv[ni] = *(const short8*)&Bs[(bn0 + ni * 16) * 64 + pos * 8];
#pragma unroll
                for (int mi = 0; mi < 2; ++mi)
#pragma unroll
                    for (int ni = 0; ni < 4; ++ni)
                        acc[mi][ni] = __builtin_amdgcn_mfma_f32_16x16x32_bf16(
                            af[mi], bfv[ni], acc[mi][ni], 0, 0, 0);
            }
        }
    }

    // C/D layout: col = lane&15, row = (lane>>4)*4 + reg
    const int erow0 = wm * 32 + g * 4;
    const int ecol0 = wn * 64 + fr;

    if (OUTBF) {
        __syncthreads();
#pragma unroll
        for (int ni = 0; ni < 4; ++ni) {
            const long col = bn + ecol0 + ni * 16;
            float bv = 0.f;
            if (HAS_BIAS) bv = bias[col];
#pragma unroll
            for (int mi = 0; mi < 2; ++mi)
#pragma unroll
                for (int r = 0; r < 4; ++r) {
                    const int row = erow0 + mi * 16 + r;
                    float v = acc[mi][ni][r];
                    if (HAS_BIAS) v += bv;
                    if (ACT == 1) v = 0.5f * v * (1.0f + erff(v * 0.70710678118654752f));
                    if (ACT == 2) v = tanhf(v);
                    if (HAS_RES) v += R[(bm + row) * N + col];
                    lds[row * 136 + ecol0 + ni * 16] = f2b(v);
                }
        }
        __syncthreads();
        const int srow2 = tid >> 4;                // 0..31
        const int sch2 = tid & 15;
        u16* Cp = (u16*)Cout;
#pragma unroll
        for (int rr = 0; rr < 4; ++rr) {
            const int row = srow2 + rr * 32;
            u16x8 vv = *(const u16x8*)&lds[row * 136 + sch2 * 8];
            *(u16x8*)(Cp + (bm + row) * N + bn + sch2 * 8) = vv;
        }
    } else {
#pragma unroll
        for (int ni = 0; ni < 4; ++ni) {
            const long col = bn + ecol0 + ni * 16;
            float bv = 0.f;
            if (HAS_BIAS) bv = bias[col];
#pragma unroll
            for (int mi = 0; mi < 2; ++mi)
#pragma unroll
                for (int r = 0; r < 4; ++r) {
                    const long row = bm + erow0 + mi * 16 + r;
                    float v = acc[mi][ni][r];
                    if (HAS_BIAS) v += bv;
                    if (ACT == 1) v = 0.5f * v * (1.0f + erff(v * 0.70710678118654752f));
                    if (ACT == 2) v = tanhf(v);
                    if (HAS_RES) v += R[row * N + col];
                    ((float*)Cout)[row * N + col] = v;
                }
        }
    }
}

// ---------------------------------------------------------------------------
// MFMA flash attention (unchanged from R6: 45 us/dispatch, no spill).
// ---------------------------------------------------------------------------
__global__ __launch_bounds__(256, 2)
void attn_kernel(const u16* __restrict__ QKV, u16* __restrict__ O) {
    const int qblk = blockIdx.x;
    const int h = blockIdx.y;
    const int b = blockIdx.z;
    const int tid = threadIdx.x;
    const int lane = tid & 63;
    const int w = tid >> 6;
    const int fr = lane & 15;
    const int g = lane >> 4;
    const int q8 = g * 8;

    __shared__ __align__(16) u16 Ks[64 * 64];     // [key][64d] swizzled
    __shared__ __align__(16) u16 Vt[64 * 72];     // [d][key] padded
    __shared__ __align__(16) u16 Pw[4][32 * 72];  // per-wave P[q][key]

    const long rowb = (long)b * TT;
    const int wq0 = qblk * 128 + w * 32;

    short8 qf[2][2];
#pragma unroll
    for (int qt = 0; qt < 2; ++qt)
#pragma unroll
        for (int hf = 0; hf < 2; ++hf)
            qf[qt][hf] = *(const short8*)(QKV + (rowb + wq0 + qt * 16 + fr) * 1536
                                          + h * 64 + hf * 32 + q8);

    f32x4 accO[2][4];
    float lsum[2][4];
#pragma unroll
    for (int qt = 0; qt < 2; ++qt) {
#pragma unroll
        for (int nt = 0; nt < 4; ++nt) accO[qt][nt] = {0.f, 0.f, 0.f, 0.f};
#pragma unroll
        for (int r = 0; r < 4; ++r) lsum[qt][r] = 0.f;
    }

    const int skey = tid >> 2;              // 0..63
    const int skc = (tid & 3) * 2;          // chunks skc, skc+1
    const int koff0 = skey * 64 + ((skc ^ (skey & 7)) * 8);
    const int koff1 = skey * 64 + (((skc + 1) ^ (skey & 7)) * 8);
    const int vkp = tid & 31;               // keys 2vkp, 2vkp+1
    const int vd0 = (tid >> 5) * 8;         // 8 d values

    auto load_kv = [&](int kt_, u16x8* kr_, u16x8* vr_) {
        const long tb_ = (rowb + (long)kt_ * 64) * 1536 + h * 64;
        const u16* kp_ = QKV + tb_ + 512 + (long)skey * 1536 + skc * 8;
        kr_[0] = *(const u16x8*)kp_;
        kr_[1] = *(const u16x8*)(kp_ + 8);
        const u16* vp_ = QKV + tb_ + 1024 + (long)(vkp * 2) * 1536 + vd0;
        vr_[0] = *(const u16x8*)vp_;
        vr_[1] = *(const u16x8*)(vp_ + 1536);
    };
    auto stage = [&](u16x8* kr_, u16x8* vr_) {
        *(u16x8*)&Ks[koff0] = kr_[0];
        *(u16x8*)&Ks[koff1] = kr_[1];
        unsigned* Vt32 = (unsigned*)Vt;
#pragma unroll
        for (int j = 0; j < 8; ++j)
            Vt32[(vd0 + j) * 36 + vkp] =
                (unsigned)vr_[0][j] | ((unsigned)vr_[1][j] << 16);
    };
    auto compute = [&]() {
        f32x4 accS[2][4];
#pragma unroll
        for (int qt = 0; qt < 2; ++qt)
#pragma unroll
            for (int n = 0; n < 4; ++n) accS[qt][n] = {0.f, 0.f, 0.f, 0.f};
#pragma unroll
        for (int n = 0; n < 4; ++n)
#pragma unroll
            for (int hf = 0; hf < 2; ++hf) {
                short8 bk = *(const short8*)&Ks[(n * 16 + fr) * 64
                                                + ((((hf << 2) + g) ^ (fr & 7)) * 8)];
                accS[0][n] = __builtin_amdgcn_mfma_f32_16x16x32_bf16(qf[0][hf], bk, accS[0][n], 0, 0, 0);
                accS[1][n] = __builtin_amdgcn_mfma_f32_16x16x32_bf16(qf[1][hf], bk, accS[1][n], 0, 0, 0);
            }
#pragma unroll
        for (int qt = 0; qt < 2; ++qt)
#pragma unroll
            for (int r = 0; r < 4; ++r) {
                int prow = qt * 16 + g * 4 + r;
#pragma unroll
                for (int n = 0; n < 4; ++n) {
                    float pv = exp2f(accS[qt][n][r] * 0.18033688011112042f);
                    lsum[qt][r] += pv;
                    Pw[w][prow * 72 + n * 16 + fr] = f2b_fast(pv);
                }
            }
#pragma unroll
        for (int hf = 0; hf < 2; ++hf) {
            short8 pa0 = *(const short8*)&Pw[w][fr * 72 + hf * 32 + q8];
            short8 pa1 = *(const short8*)&Pw[w][(16 + fr) * 72 + hf * 32 + q8];
#pragma unroll
            for (int nt = 0; nt < 4; ++nt) {
                short8 bv = *(const short8*)&Vt[(nt * 16 + fr) * 72 + hf * 32 + q8];
                accO[0][nt] = __builtin_amdgcn_mfma_f32_16x16x32_bf16(pa0, bv, accO[0][nt], 0, 0, 0);
                accO[1][nt] = __builtin_amdgcn_mfma_f32_16x16x32_bf16(pa1, bv, accO[1][nt], 0, 0, 0);
            }
        }
    };

    u16x8 krA[2], vrA[2], krB[2], vrB[2];
    load_kv(0, krA, vrA);

#pragma unroll 1
    for (int kt = 0; kt < 16; kt += 2) {
        __syncthreads();                    // prior tile fully consumed
        stage(krA, vrA);
        load_kv(kt + 1, krB, vrB);          // in flight through compute(kt)
        __syncthreads();                    // staged tile visible
        compute();
        __syncthreads();
        stage(krB, vrB);
        if (kt + 2 < 16) load_kv(kt + 2, krA, vrA);
        __syncthreads();
        compute();
    }

#pragma unroll
    for (int qt = 0; qt < 2; ++qt)
#pragma unroll
        for (int r = 0; r < 4; ++r) {
            float s = lsum[qt][r];
            s += __shfl_xor(s, 1, 64);
            s += __shfl_xor(s, 2, 64);
            s += __shfl_xor(s, 4, 64);
            s += __shfl_xor(s, 8, 64);
            lsum[qt][r] = 1.0f / s;
        }
#pragma unroll
    for (int qt = 0; qt < 2; ++qt)
#pragma unroll
        for (int nt = 0; nt < 4; ++nt)
#pragma unroll
            for (int r = 0; r < 4; ++r) {
                long row = rowb + wq0 + qt * 16 + g * 4 + r;
                O[row * DD + h * 64 + nt * 16 + fr] = f2b(accO[qt][nt][r] * lsum[qt][r]);
            }
}

// ---------------------------------------------------------------------------
// Weight prep. wprep512_kernel: nineteen 512x512 transposes via pointer table.
// ---------------------------------------------------------------------------
struct WP   { const float* s; u16* d; };
struct WTbl { WP e[19]; };

__global__ __launch_bounds__(256)
void wprep512_kernel(WTbl tbl) {
    const float* src = tbl.e[blockIdx.z].s;
    u16* dst = tbl.e[blockIdx.z].d;
    int k0 = blockIdx.y * 32, n0 = blockIdx.x * 32;
    __shared__ float tile[32][33];
    int tx = threadIdx.x & 31, ty = threadIdx.x >> 5;
#pragma unroll
    for (int i = 0; i < 4; ++i)
        tile[ty + 8 * i][tx] = src[(long)(k0 + ty + 8 * i) * 512 + n0 + tx];
    __syncthreads();
#pragma unroll
    for (int i = 0; i < 4; ++i) {
        int r = ty + 8 * i;
        dst[(long)(n0 + r) * 512 + k0 + tx] = f2b(tile[tx][r]);
    }
}

__global__ __launch_bounds__(256)
void wprep_kernel(const float* __restrict__ src, u16* __restrict__ dst,
                  int K, int N, long srcLS, long dstLS) {
    int l = blockIdx.z;
    src += (long)l * srcLS;
    dst += (long)l * dstLS;
    int k0 = blockIdx.y * 32, n0 = blockIdx.x * 32;
    __shared__ float tile[32][33];
    int tx = threadIdx.x & 31, ty = threadIdx.x >> 5;
#pragma unroll
    for (int i = 0; i < 4; ++i)
        tile[ty + 8 * i][tx] = src[(long)(k0 + ty + 8 * i) * N + n0 + tx];
    __syncthreads();
#pragma unroll
    for (int i = 0; i < 4; ++i) {
        int r = ty + 8 * i;
        dst[(long)(n0 + r) * K + k0 + tx] = f2b(tile[tx][r]);
    }
}

__global__ __launch_bounds__(256)
void bprep_kernel(const float* __restrict__ bq, const float* __restrict__ bk,
                  const float* __restrict__ bv, float* __restrict__ dst) {
    int i = blockIdx.x * 256 + threadIdx.x;
    int l = i / 1536, j = i - l * 1536;
    float v = (j < 512) ? bq[l * 512 + j]
            : (j < 1024) ? bk[l * 512 + j - 512]
                         : bv[l * 512 + j - 1024];
    dst[i] = v;
}

__global__ __launch_bounds__(256)
void f2b_kernel(const float* __restrict__ in, u16* __restrict__ out, int n) {
    int i = blockIdx.x * 256 + threadIdx.x;
    if (i < n) out[i] = f2b(in[i]);
}

__global__ __launch_bounds__(256)
void zero_kernel(float* __restrict__ p, int n) {
    int i = blockIdx.x * 256 + threadIdx.x;
    if (i < n) p[i] = 0.0f;
}

__global__ __launch_bounds__(256)
void colmean_kernel(const float* __restrict__ Hn, float* __restrict__ XM) {
    int blk = blockIdx.x;
    int b = blk >> 5;
    int r0 = (blk & 31) * 32;
    int tid = threadIdx.x;
    float acc0 = 0.0f, acc1 = 0.0f;
    for (int r = 0; r < 32; ++r) {
        long off = ((long)b * TT + r0 + r) * DD + tid;
        acc0 += Hn[off];
        acc1 += Hn[off + 256];
    }
    atomicAdd(&XM[b * DD + tid], acc0);
    atomicAdd(&XM[b * DD + tid + 256], acc1);
}

__global__ __launch_bounds__(256)
void cls_kernel(const float* __restrict__ XM, const float* __restrict__ W,
                const float* __restrict__ bias, float* __restrict__ out) {
    int b = blockIdx.x;
    int tid = threadIdx.x;
    __shared__ float xm[DD];
    xm[tid] = XM[b * DD + tid] * (1.0f / TT);
    xm[tid + 256] = XM[b * DD + tid + 256] * (1.0f / TT);
    __syncthreads();
    if (tid < NCC) {
        float s = bias[tid];
        for (int d = 0; d < DD; ++d) s += xm[d] * W[d * NCC + tid];
        out[b * NCC + tid] = s;
    }
}

// ---------------------------------------------------------------------------
extern "C" void kernel_launch(void* const* d_in, const int* in_sizes, int n_in,
                              void* d_out, int out_size, void* d_ws, size_t ws_size,
                              hipStream_t stream) {
    const int*   tokens  = (const int*)d_in[0];
    const float* emb     = (const float*)d_in[1];
    const float* Wq      = (const float*)d_in[2];
    const float* bq      = (const float*)d_in[3];
    const float* Wk      = (const float*)d_in[4];
    const float* bk      = (const float*)d_in[5];
    const float* Wv      = (const float*)d_in[6];
    const float* bv      = (const float*)d_in[7];
    const float* Wo      = (const float*)d_in[8];
    const float* bo      = (const float*)d_in[9];
    const float* ln1_g   = (const float*)d_in[10];
    const float* ln1_b   = (const float*)d_in[11];
    const float* ln2_g   = (const float*)d_in[12];
    const float* ln2_b   = (const float*)d_in[13];
    const float* W1      = (const float*)d_in[14];
    const float* b1      = (const float*)d_in[15];
    const float* W2      = (const float*)d_in[16];
    const float* b2      = (const float*)d_in[17];
    const float* heavy_w = (const float*)d_in[18];
    const float* heavy_b = (const float*)d_in[19];
    const float* heavy_a1= (const float*)d_in[20];
    const float* heavy_a2= (const float*)d_in[21];
    const float* norm_g  = (const float*)d_in[22];
    const float* norm_b  = (const float*)d_in[23];
    const float* cls_W   = (const float*)d_in[24];
    const float* cls_b   = (const float*)d_in[25];
    float* out = (float*)d_out;

    char* p = (char*)d_ws;
    float* X    = (float*)p;  p += MDl * 4;
    u16*   Hh   = (u16*)p;    p += MDl * 2;
    u16*   QKVb = (u16*)p;
    u16*   FFb  = QKVb;
    u16*   T1   = QKVb;
    u16*   T2   = QKVb + MDl;
    float* LNout= (float*)QKVb;
    p += (long)MM * 1536 * 2;
    u16*   Ob   = (u16*)p;    p += MDl * 2;
    u16*   Xbf  = (u16*)p;    p += MDl * 2;
    u16*   WqkvT= (u16*)p;    p += 4L * 1536 * 512 * 2;
    u16*   WoT  = (u16*)p;    p += 4L * 512 * 512 * 2;
    u16*   W1T  = (u16*)p;    p += 4L * 2048 * 512 * 2;
    u16*   W2T  = (u16*)p;    p += 4L * 512 * 2048 * 2;
    u16*   WhT  = (u16*)p;    p += 3L * 512 * 512 * 2;
    float* bqkv = (float*)p;  p += 4L * 1536 * 4;
    float* XM   = (float*)p;  p += (long)BS * DD * 4;

    dim3 blk(256);
    dim3 blk512(512);

    WTbl tbl;
    for (int l = 0; l < 4; ++l) {
        tbl.e[l * 4 + 0] = {Wq + (long)l * 262144, WqkvT + (long)l * 786432};
        tbl.e[l * 4 + 1] = {Wk + (long)l * 262144, WqkvT + (long)l * 786432 + 262144};
        tbl.e[l * 4 + 2] = {Wv + (long)l * 262144, WqkvT + (long)l * 786432 + 524288};
        tbl.e[l * 4 + 3] = {Wo + (long)l * 262144, WoT + (long)l * 262144};
    }
    tbl.e[16] = {heavy_w,  WhT};
    tbl.e[17] = {heavy_a1, WhT + 262144};
    tbl.e[18] = {heavy_a2, WhT + 524288};
    wprep512_kernel<<<dim3(16, 16, 19), blk, 0, stream>>>(tbl);
    wprep_kernel<<<dim3(64, 16, 4), blk, 0, stream>>>(W1, W1T,  512, 2048, 1048576, 1048576);
    wprep_kernel<<<dim3(16, 64, 4), blk, 0, stream>>>(W2, W2T, 2048,  512, 1048576, 1048576);
    bprep_kernel<<<24, blk, 0, stream>>>(bq, bk, bv, bqkv);

    embed_kernel<<<MM * DD / 256, blk, 0, stream>>>(tokens, emb, X);

    dim3 gQKV(12, 64), g512(4, 64), gFF1(16, 64);

    for (int l = 0; l < LL; ++l) {
        ln_kernel<1><<<MM, blk, 0, stream>>>(X, Hh, ln1_g + l * DD, ln1_b + l * DD);
        mfma_gemm<1, 1, 0, 0><<<gQKV, blk512, 0, stream>>>(
            Hh, WqkvT + (long)l * 786432, bqkv + l * 1536, nullptr, QKVb, 1536, 512);
        attn_kernel<<<dim3(8, HH, BS), blk, 0, stream>>>(QKVb, Ob);
        mfma_gemm<0, 1, 0, 1><<<g512, blk512, 0, stream>>>(
            Ob, WoT + (long)l * 262144, bo + l * DD, X, X, 512, 512);
        ln_kernel<1><<<MM, blk, 0, stream>>>(X, Hh, ln2_g + l * DD, ln2_b + l * DD);
        mfma_gemm<1, 1, 1, 0><<<gFF1, blk512, 0, stream>>>(
            Hh, W1T + (long)l * 1048576, b1 + l * FFD, nullptr, FFb, 2048, 512);
        mfma_gemm<0, 1, 0, 1><<<g512, blk512, 0, stream>>>(
            FFb, W2T + (long)l * 1048576, b2 + l * DD, X, X, 512, 2048);
    }

    f2b_kernel<<<MM * DD / 256, blk, 0, stream>>>(X, Xbf, MM * DD);
    mfma_gemm<1, 0, 0, 0><<<g512, blk512, 0, stream>>>(Xbf, WhT,          nullptr, nullptr, T1, 512, 512);
    mfma_gemm<1, 0, 0, 0><<<g512, blk512, 0, stream>>>(T1,  WhT + 262144, nullptr, nullptr, T2, 512, 512);
    mfma_gemm<0, 1, 2, 0><<<g512, blk512, 0, stream>>>(T2,  WhT + 524288, heavy_b, nullptr, X,  512, 512);

    ln_kernel<0><<<MM, blk, 0, stream>>>(X, LNout, norm_g, norm_b);
    zero_kernel<<<(BS * DD + 255) / 256, blk, 0, stream>>>(XM, BS * DD);
    colmean_kernel<<<256, blk, 0, stream>>>(LNout, XM);
    cls_kernel<<<BS, blk, 0, stream>>>(XM, cls_W, cls_b, out);
}